// Round 8
// baseline (1059.205 us; speedup 1.0000x reference)
//
#include <hip/hip_runtime.h>
#include <hip/hip_bf16.h>

// MultiAttention: S=1024, B=8, D=1024, H=8
// Round 8: deeper-pipelined 8-phase engine. Reads concentrated early (all-A +
// B01 in ph1, B23 in ph2) so every LDS region frees early; stage slots spread
// ph1-ph8 with 3 half-tiles in flight -> counted vmcnt(6) at both waits
// (m201/T4 discipline). Applied to QKV/scores/PV/outproj. Glue unchanged.
// ws peak 365 MiB.

typedef __attribute__((ext_vector_type(8))) __bf16 bf16x8;
typedef __attribute__((ext_vector_type(4))) float f32x4;

__device__ __forceinline__ unsigned short f2bf(float f) {
  union { float f; unsigned u; } x; x.f = f;
  unsigned r = x.u + 0x7fffu + ((x.u >> 16) & 1u);   // RNE
  return (unsigned short)(r >> 16);
}

__device__ __forceinline__ void gload16(const void* g, void* l) {
  __builtin_amdgcn_global_load_lds(
      (const __attribute__((address_space(1))) void*)g,
      (__attribute__((address_space(3))) void*)l, 16, 0, 0);
}

#define SBAR()  do { __builtin_amdgcn_sched_barrier(0); __builtin_amdgcn_s_barrier(); \
                     __builtin_amdgcn_sched_barrier(0); } while (0)
#define LGKM0() do { asm volatile("s_waitcnt lgkmcnt(0)" ::: "memory"); \
                     __builtin_amdgcn_sched_barrier(0); } while (0)
#define VMC6()  do { asm volatile("s_waitcnt vmcnt(6)" ::: "memory"); \
                     __builtin_amdgcn_sched_barrier(0); } while (0)

// ================= 256x256 8-phase NT GEMM (vmcnt(6) schedule) ================
// C = alpha*(A @ B^T) [+bias[col]].  Batched: z, h=z/nb, b=z%nb.
// K % 128 == 0, K >= 128. 512 threads, LDS 128 KiB (2 x 64 KiB buffers).
// Buffer layout: A.h0 @ +0, A.h1 @ +16384, B.h0 @ +32768, B.h1 @ +49152.
struct Frags { bf16x8 aF[8][2]; bf16x8 bF[4][2]; };

// ph1 reads: ALL A fragments + B rows 0-1 (20 x ds_read_b128)
__device__ __forceinline__ void qr1(const char* sm, int bb, int aRow, int bRow,
                                    int kx0, int kx1, Frags& fr)
{
#pragma unroll
  for (int m = 0; m < 8; ++m) {
    fr.aF[m][0] = *(const bf16x8*)(sm + bb + aRow + m * 2048 + kx0);
    fr.aF[m][1] = *(const bf16x8*)(sm + bb + aRow + m * 2048 + kx1);
  }
#pragma unroll
  for (int n = 0; n < 2; ++n) {
    fr.bF[n][0] = *(const bf16x8*)(sm + bb + bRow + n * 2048 + kx0);
    fr.bF[n][1] = *(const bf16x8*)(sm + bb + bRow + n * 2048 + kx1);
  }
}
// ph2 reads: B rows 2-3 (4 x ds_read_b128)
__device__ __forceinline__ void qr2(const char* sm, int bb, int bRow,
                                    int kx0, int kx1, Frags& fr)
{
#pragma unroll
  for (int n = 2; n < 4; ++n) {
    fr.bF[n][0] = *(const bf16x8*)(sm + bb + bRow + n * 2048 + kx0);
    fr.bF[n][1] = *(const bf16x8*)(sm + bb + bRow + n * 2048 + kx1);
  }
}

template<int QUAD>
__device__ __forceinline__ void qmfma(f32x4 acc[8][4], Frags& fr)
{
  constexpr int mo = (QUAD >= 2) ? 4 : 0;
  constexpr int no = (QUAD == 1 || QUAD == 2) ? 2 : 0;
  __builtin_amdgcn_s_setprio(1);
#pragma unroll
  for (int m = 0; m < 4; ++m)
#pragma unroll
    for (int n = 0; n < 2; ++n)
#pragma unroll
      for (int ks = 0; ks < 2; ++ks)
        acc[mo + m][no + n] = __builtin_amdgcn_mfma_f32_16x16x32_bf16(
            fr.aF[mo + m][ks], fr.bF[no + n][ks], acc[mo + m][no + n], 0, 0, 0);
  __builtin_amdgcn_s_setprio(0);
  __builtin_amdgcn_sched_barrier(0);
}

template<int OUT_BF16, int HAS_BIAS, int NT_FAST>
__global__ __launch_bounds__(512, 2)
void gemm256_nt(const unsigned short* __restrict__ A,
                const unsigned short* __restrict__ B,
                void* __restrict__ C,
                const float* __restrict__ bias,
                float alpha, int K,
                long lda, long ldb, long ldc,
                long offA_h, long offA_b,
                long offB_h, long offB_b,
                long offC_h, long offC_b,
                int MT, int NTt, int nb)
{
  __shared__ __align__(16) char sm[131072];

  const int nwg = gridDim.x;
  const int swz = (blockIdx.x & 7) * (nwg >> 3) + (blockIdx.x >> 3);
  const int per_z = MT * NTt;
  const int z = swz / per_z;
  const int r = swz - z * per_z;
  const int mt = NT_FAST ? (r / NTt) : (r % MT);
  const int nt = NT_FAST ? (r % NTt) : (r / MT);
  const int h = z / nb, bz = z - h * nb;

  const unsigned short* Ablk = A + h * offA_h + bz * offA_b + (long)mt * 256 * lda;
  const unsigned short* Bblk = B + h * offB_h + bz * offB_b + (long)nt * 256 * ldb;

  const int tid  = threadIdx.x;
  const int lane = tid & 63;
  const int w    = tid >> 6;
  const int wr   = w >> 2, wc = w & 3;

  const int rA  = tid >> 3;
  const int cSw = (tid ^ (tid >> 3)) & 7;

  const int aRow = wr * 16384 + (lane & 15) * 128;
  const int bRow = 32768 + (wc >> 1) * 16384 + ((wc & 1) * 64 + (lane & 15)) * 128;
  const int kq = (lane >> 4) * 16, sw = (lane & 7) << 4;
  const int kx0 = kq ^ sw;
  const int kx1 = (64 + kq) ^ sw;

  const int NT = K >> 6;        // BK=64 tiles (NT >= 2)
  const int NIT = NT >> 1;

  f32x4 acc[8][4] = {};
  Frags fr;

  auto stageA = [&](int half, int kt, int region) {
    const unsigned short* g = Ablk + ((long)(half * 128) + rA) * lda + (long)kt * 64 + cSw * 8;
    gload16(g,            sm + region + tid * 16);
    gload16(g + 64 * lda, sm + region + 8192 + tid * 16);
  };
  auto stageB = [&](int half, int kt, int region) {
    const unsigned short* g = Bblk + ((long)(half * 128) + rA) * ldb + (long)kt * 64 + cSw * 8;
    gload16(g,            sm + region + tid * 16);
    gload16(g + 64 * ldb, sm + region + 8192 + tid * 16);
  };

  // prologue: tile0 -> buf0 (8 loads), tile1 A.h0/A.h1/B.h0 -> buf1 (6 loads)
  stageA(0, 0, 0);
  stageA(1, 0, 16384);
  stageB(0, 0, 32768);
  stageB(1, 0, 49152);
  stageA(0, 1, 65536);
  stageA(1, 1, 65536 + 16384);
  stageB(0, 1, 65536 + 32768);
  VMC6();            // drains tile0; tile1's 6 loads stay in flight
  SBAR();

#pragma unroll 1
  for (int it = 0; it < NIT; ++it) {
    const int ktB = 2 * it + 1;                               // buf1 tail
    const int kt2a = 2 * it + 2, kt2 = kt2a < NT ? kt2a : NT - 1;
    const int kt3a = 2 * it + 3, kt3 = kt3a < NT ? kt3a : NT - 1;

    // ---- K-tile 2it from buf0 ----
    qr1(sm, 0, aRow, bRow, kx0, kx1, fr);
    stageB(1, ktB, 65536 + 49152);        // buf1.B.h1 (tile 2it+1, tail)
    SBAR(); LGKM0(); qmfma<0>(acc, fr); SBAR();

    qr2(sm, 0, bRow, kx0, kx1, fr);
    stageA(0, kt2, 0);                    // buf0.A.h0 (tile 2it+2)
    SBAR(); LGKM0(); qmfma<1>(acc, fr); SBAR();

    stageA(1, kt2, 16384);                // buf0.A.h1
    SBAR(); LGKM0(); qmfma<2>(acc, fr); SBAR();

    stageB(0, kt2, 32768);                // buf0.B.h0
    SBAR(); LGKM0(); qmfma<3>(acc, fr);
    VMC6();                               // tile 2it+1 fully landed
    SBAR();

    // ---- K-tile 2it+1 from buf1 ----
    qr1(sm, 65536, aRow, bRow, kx0, kx1, fr);
    stageB(1, kt2, 49152);                // buf0.B.h1 (tile 2it+2, tail)
    SBAR(); LGKM0(); qmfma<0>(acc, fr); SBAR();

    qr2(sm, 65536, bRow, kx0, kx1, fr);
    stageA(0, kt3, 65536);                // buf1.A.h0 (tile 2it+3)
    SBAR(); LGKM0(); qmfma<1>(acc, fr); SBAR();

    stageA(1, kt3, 65536 + 16384);        // buf1.A.h1
    SBAR(); LGKM0(); qmfma<2>(acc, fr); SBAR();

    stageB(0, kt3, 65536 + 32768);        // buf1.B.h0
    SBAR(); LGKM0(); qmfma<3>(acc, fr);
    VMC6();                               // tile 2it+2 fully landed
    SBAR();
  }

  // epilogue: C/D layout col = lane&15, row = (lane>>4)*4 + j
  const long crow0 = (long)mt * 256 + wr * 128;
  const long ccol0 = (long)nt * 256 + wc * 64;
  const long cbase = h * offC_h + bz * offC_b;
#pragma unroll
  for (int m = 0; m < 8; ++m)
#pragma unroll
    for (int n = 0; n < 4; ++n) {
      const long col = ccol0 + n * 16 + (lane & 15);
      const float badd = HAS_BIAS ? bias[col] : 0.0f;
#pragma unroll
      for (int j = 0; j < 4; ++j) {
        const long row = crow0 + m * 16 + (lane >> 4) * 4 + j;
        const float v = acc[m][n][j] * alpha + badd;
        const long idx = cbase + row * ldc + col;
        if (OUT_BF16) ((unsigned short*)C)[idx] = f2bf(v);
        else          ((float*)C)[idx] = v;
      }
    }
}

// ---------------- softmax over rows of 1024 (fp32 in, bf16 out) ---------------
__global__ __launch_bounds__(256)
void softmax_k(const float* __restrict__ SC, unsigned short* __restrict__ P)
{
  const long row = blockIdx.x;
  const float* s = SC + (row << 10);
  unsigned short* p = P + (row << 10);
  const int tid = threadIdx.x;

  float4 v = ((const float4*)s)[tid];
  float mx = fmaxf(fmaxf(v.x, v.y), fmaxf(v.z, v.w));
#pragma unroll
  for (int o = 32; o >= 1; o >>= 1) mx = fmaxf(mx, __shfl_xor(mx, o));
  __shared__ float red[8];
  const int w = tid >> 6, lane = tid & 63;
  if (lane == 0) red[w] = mx;
  __syncthreads();
  mx = fmaxf(fmaxf(red[0], red[1]), fmaxf(red[2], red[3]));

  float e0 = __expf(v.x - mx), e1 = __expf(v.y - mx);
  float e2 = __expf(v.z - mx), e3 = __expf(v.w - mx);
  float sum = e0 + e1 + e2 + e3;
#pragma unroll
  for (int o = 32; o >= 1; o >>= 1) sum += __shfl_xor(sum, o);
  if (lane == 0) red[4 + w] = sum;
  __syncthreads();
  sum = red[4] + red[5] + red[6] + red[7];
  const float inv = 1.0f / sum;

  ushort4 o4;
  o4.x = f2bf(e0 * inv); o4.y = f2bf(e1 * inv);
  o4.z = f2bf(e2 * inv); o4.w = f2bf(e3 * inv);
  ((ushort4*)p)[tid] = o4;
}

// ---- V transpose: VT[z][e][t] = src[h*hStr + b*bStr + t*tStr + e], z=h*8+b ---
__global__ __launch_bounds__(256)
void transpose_v(const unsigned short* __restrict__ src, unsigned short* __restrict__ VT,
                 long tStr, long hStr, long bStr)
{
  const int z = blockIdx.z;
  const int hh = z >> 3, b = z & 7;
  const unsigned short* s = src + hh * hStr + b * bStr;
  __shared__ unsigned short tile[32][33];
  const int t0 = blockIdx.x * 32, e0 = blockIdx.y * 32;
  const int tx = threadIdx.x & 31, ty = threadIdx.x >> 5;
#pragma unroll
  for (int i = 0; i < 4; ++i) {
    const int tr = ty + i * 8;
    tile[tr][tx] = s[(long)(t0 + tr) * tStr + e0 + tx];
  }
  __syncthreads();
#pragma unroll
  for (int i = 0; i < 4; ++i) {
    const int er = ty + i * 8;
    VT[(long)z * 1048576 + (long)(e0 + er) * 1024 + t0 + tx] = tile[tx][er];
  }
}

// ---------------- converters / epilogue add -----------------------------------
__global__ __launch_bounds__(256)
void conv_bf16(const float* __restrict__ in, unsigned short* __restrict__ out, long n4)
{
  const long i = (long)blockIdx.x * 256 + threadIdx.x;
  if (i >= n4) return;
  const float4 v = ((const float4*)in)[i];
  ushort4 o; o.x = f2bf(v.x); o.y = f2bf(v.y); o.z = f2bf(v.z); o.w = f2bf(v.w);
  ((ushort4*)out)[i] = o;
}

// w_out [h][f][e] -> Wob[f][h*1024+e]
__global__ __launch_bounds__(256)
void conv_wout(const float* __restrict__ in, unsigned short* __restrict__ out)
{
  const long i = (long)blockIdx.x * 256 + threadIdx.x;   // 2M float4s
  const long o = i << 2;
  const long f = o >> 13, r = o & 8191;
  const long h = r >> 10, e = r & 1023;
  const float4 v = *(const float4*)(in + h * 1048576 + f * 1024 + e);
  ushort4 u; u.x = f2bf(v.x); u.y = f2bf(v.y); u.z = f2bf(v.z); u.w = f2bf(v.w);
  *(ushort4*)(out + o) = u;
}

__global__ __launch_bounds__(256)
void bias_sum_k(const float* __restrict__ b_out, float* __restrict__ bsum)
{
  const int f = blockIdx.x * 256 + threadIdx.x;
  if (f < 1024) {
    float s = 0.f;
#pragma unroll
    for (int h = 0; h < 8; ++h) s += b_out[h * 1024 + f];
    bsum[f] = s;
  }
}

// out = p[0] + p[1] + bsum   (2M float4)
__global__ __launch_bounds__(256)
void add_out_k(const float* __restrict__ p, float* __restrict__ out,
               const float* __restrict__ bsum)
{
  const long i = (long)blockIdx.x * 256 + threadIdx.x;
  const float4 a = ((const float4*)p)[i];
  const float4 b = ((const float4*)(p + 8388608))[i];
  const float4 s = ((const float4*)bsum)[i & 255];
  float4 o;
  o.x = a.x + b.x + s.x; o.y = a.y + b.y + s.y;
  o.z = a.z + b.z + s.z; o.w = a.w + b.w + s.w;
  ((float4*)out)[i] = o;
}

// ---------------- launch ------------------------------------------------------
extern "C" void kernel_launch(void* const* d_in, const int* in_sizes, int n_in,
                              void* d_out, int out_size, void* d_ws, size_t ws_size,
                              hipStream_t stream)
{
  const float* x     = (const float*)d_in[0];
  const float* w_in  = (const float*)d_in[1];
  const float* b_in  = (const float*)d_in[2];
  const float* w_out = (const float*)d_in[3];
  const float* b_out = (const float*)d_in[4];
  float* out = (float*)d_out;

  char* ws = (char*)d_ws;
  const long MB = 1ll << 20;
  unsigned short* Xb   = (unsigned short*)(ws);              // 16 MiB
  unsigned short* Wob  = (unsigned short*)(ws + 16 * MB);    // 16 MiB
  float*          bsum = (float*)         (ws + 32 * MB);    // 4 KiB
  unsigned short* Ocat = (unsigned short*)(ws + 33 * MB);    // 128 MiB
  unsigned short* Wbg  = (unsigned short*)(ws + 161 * MB);   // 12 MiB
  unsigned short* QKVg = (unsigned short*)(ws + 173 * MB);   // 96 MiB
  float*          SCg  = (float*)         (ws + 269 * MB);   // 64 MiB
  unsigned short* Pg   = (unsigned short*)(ws + 333 * MB);   // 32 MiB -> 365 MiB
  unsigned short* VT   = (unsigned short*)SCg;               // alias (SC dead post-softmax)
  float*          Opart = (float*)        (ws + 269 * MB);   // 64 MiB alias (post-attention)

  dim3 blk(256), blk512(512);

  conv_bf16 <<<8192, blk, 0, stream>>>(x, Xb, 2097152);
  conv_wout <<<8192, blk, 0, stream>>>(w_out, Wob);
  bias_sum_k<<<4,    blk, 0, stream>>>(b_out, bsum);

  for (int g = 0; g < 4; ++g) {
    // weights for heads 2g, 2g+1: [6144][1024] bf16
    conv_bf16<<<6144, blk, 0, stream>>>(w_in + (long)g * 6291456, Wbg, 1572864);

    // QKVg[sb][hh*3072 + sec*1024 + e] = Xb @ Wbg^T + b_in[g-rows]
    gemm256_nt<1,1,0><<<768, blk512, 0, stream>>>(
        Xb, Wbg, QKVg, b_in + (long)g * 6144, 1.0f, 1024,
        1024, 1024, 6144,  0, 0,  0, 0,  0, 0,  32, 24, 1);

    // scores: z = hh*8+b: SCg[z][s][t] = (Q K^T)/32, fp32 (256 blocks, 1/CU)
    gemm256_nt<0,0,0><<<256, blk512, 0, stream>>>(
        QKVg, QKVg + 1024, SCg, nullptr, 0.03125f, 1024,
        49152, 49152, 1024,  3072, 6144,  3072, 6144,  8388608, 1048576,  4, 4, 8);

    softmax_k<<<16384, blk, 0, stream>>>(SCg, Pg);

    // VT[z][e][t] = V[(t*8+b)*6144 + hh*3072 + 2048 + e]
    transpose_v<<<dim3(32, 32, 16), blk, 0, stream>>>(
        QKVg + 2048, VT, 49152, 3072, 6144);

    // PV: Ocat[(s*8+b)*8192 + (2g+hh)*1024 + e] = sum_t P[z][s][t] VT[z][e][t]
    gemm256_nt<1,0,0><<<256, blk512, 0, stream>>>(
        Pg, VT, Ocat + (long)g * 2048, nullptr, 1.0f, 1024,
        1024, 1024, 65536,  8388608, 1048576,  8388608, 1048576,  1024, 8192,  4, 4, 8);
  }

  // outproj K-split: Opart[z] = Ocat[:, z*4096:(z+1)*4096] @ Wob[:, same]^T
  gemm256_nt<0,0,1><<<256, blk512, 0, stream>>>(
      Ocat, Wob, Opart, nullptr, 1.0f, 4096,
      8192, 8192, 1024,  0, 4096,  0, 4096,  0, 8388608,  32, 4, 2);

  add_out_k<<<8192, blk, 0, stream>>>(Opart, out, bsum);
}

// Round 10
// 947.085 us; speedup vs baseline: 1.1184x; 1.1184x over previous
//
#include <hip/hip_runtime.h>
#include <hip/hip_bf16.h>

// MultiAttention: S=1024, B=8, D=1024, H=8
// Round 10: round-9 structure + __launch_bounds__(512,1) on the GEMM engine.
// Theory: (512,2) capped VGPRs at 128 (we measured 120-128 = at-cap); round-9
// epilogues pushed past it -> scratch spills = extra VMEM ops inside the loop
// -> counted vmcnt(4) drains wrong ops -> timing-dependent LDS corruption
// (cold call passed, warm replays diverged). LDS already limits to 1 block/CU,
// so (512,1) costs nothing and restores exact vmcnt discipline.
// ws peak ~338 MiB.

typedef __attribute__((ext_vector_type(8))) __bf16 bf16x8;
typedef __attribute__((ext_vector_type(4))) float f32x4;

__device__ __forceinline__ unsigned short f2bf(float f) {
  union { float f; unsigned u; } x; x.f = f;
  unsigned r = x.u + 0x7fffu + ((x.u >> 16) & 1u);   // RNE
  return (unsigned short)(r >> 16);
}
__device__ __forceinline__ float bf2f(unsigned short u) {
  union { unsigned u; float f; } x; x.u = ((unsigned)u) << 16;
  return x.f;
}

__device__ __forceinline__ void gload16(const void* g, void* l) {
  __builtin_amdgcn_global_load_lds(
      (const __attribute__((address_space(1))) void*)g,
      (__attribute__((address_space(3))) void*)l, 16, 0, 0);
}

#define SBAR()  do { __builtin_amdgcn_sched_barrier(0); __builtin_amdgcn_s_barrier(); \
                     __builtin_amdgcn_sched_barrier(0); } while (0)
#define LGKM0() do { asm volatile("s_waitcnt lgkmcnt(0)" ::: "memory"); \
                     __builtin_amdgcn_sched_barrier(0); } while (0)
#define VMC4()  do { asm volatile("s_waitcnt vmcnt(4)" ::: "memory"); \
                     __builtin_amdgcn_sched_barrier(0); } while (0)

// ================= 256x256 8-phase NT GEMM (round-6 core) =====================
struct Frags { bf16x8 aF[4][2]; bf16x8 b0F[2][2]; bf16x8 b1F[2][2]; };

template<int QUAD>
__device__ __forceinline__ void qreads(const char* sm, int bb, int aRow, int bRow,
                                       int kx0, int kx1, Frags& fr)
{
  if constexpr (QUAD == 0) {
#pragma unroll
    for (int m = 0; m < 4; ++m) {
      fr.aF[m][0] = *(const bf16x8*)(sm + bb + aRow + m * 2048 + kx0);
      fr.aF[m][1] = *(const bf16x8*)(sm + bb + aRow + m * 2048 + kx1);
    }
#pragma unroll
    for (int n = 0; n < 2; ++n) {
      fr.b0F[n][0] = *(const bf16x8*)(sm + bb + bRow + n * 2048 + kx0);
      fr.b0F[n][1] = *(const bf16x8*)(sm + bb + bRow + n * 2048 + kx1);
    }
  } else if constexpr (QUAD == 1) {
#pragma unroll
    for (int n = 0; n < 2; ++n) {
      fr.b1F[n][0] = *(const bf16x8*)(sm + bb + bRow + (2 + n) * 2048 + kx0);
      fr.b1F[n][1] = *(const bf16x8*)(sm + bb + bRow + (2 + n) * 2048 + kx1);
    }
  } else if constexpr (QUAD == 2) {
#pragma unroll
    for (int m = 0; m < 4; ++m) {
      fr.aF[m][0] = *(const bf16x8*)(sm + bb + aRow + (4 + m) * 2048 + kx0);
      fr.aF[m][1] = *(const bf16x8*)(sm + bb + aRow + (4 + m) * 2048 + kx1);
    }
  }
}

template<int QUAD>
__device__ __forceinline__ void qmfma(f32x4 acc[8][4], Frags& fr)
{
  constexpr int mo = (QUAD >= 2) ? 4 : 0;
  constexpr int no = (QUAD == 1 || QUAD == 2) ? 2 : 0;
  __builtin_amdgcn_s_setprio(1);
#pragma unroll
  for (int m = 0; m < 4; ++m)
#pragma unroll
    for (int n = 0; n < 2; ++n)
#pragma unroll
      for (int ks = 0; ks < 2; ++ks) {
        const bf16x8 bv = (no == 0) ? fr.b0F[n][ks] : fr.b1F[n][ks];
        acc[mo + m][no + n] =
            __builtin_amdgcn_mfma_f32_16x16x32_bf16(fr.aF[m][ks], bv, acc[mo + m][no + n], 0, 0, 0);
      }
  __builtin_amdgcn_s_setprio(0);
  __builtin_amdgcn_sched_barrier(0);
}

// EPI modes: 0 = fp32 store (no bias)        [outproj]
//            1 = bf16 store + col bias       [QK]
//            2 = bf16 store + row bias       [VT]
//            3 = bf16 store of exp(alpha*v)  [scores]
//            4 = bf16 store * rowfac         [PV]
template<int EPI, int NT_FAST>
__global__ __launch_bounds__(512, 1)
void gemm256_nt(const unsigned short* __restrict__ A,
                const unsigned short* __restrict__ B,
                void* __restrict__ C,
                const float* __restrict__ bias,
                float alpha, int K,
                long lda, long ldb, long ldc,
                long offA_h, long offA_b,
                long offB_h, long offB_b,
                long offC_h, long offC_b,
                long offBias_h, long offBias_b,
                int MT, int NTt, int nb)
{
  __shared__ __align__(16) char sm[131072];

  const int nwg = gridDim.x;
  const int swz = (blockIdx.x & 7) * (nwg >> 3) + (blockIdx.x >> 3);
  const int per_z = MT * NTt;
  const int z = swz / per_z;
  const int r = swz - z * per_z;
  const int mt = NT_FAST ? (r / NTt) : (r % MT);
  const int nt = NT_FAST ? (r % NTt) : (r / MT);
  const int h = z / nb, bz = z - h * nb;

  const unsigned short* Ablk = A + h * offA_h + bz * offA_b + (long)mt * 256 * lda;
  const unsigned short* Bblk = B + h * offB_h + bz * offB_b + (long)nt * 256 * ldb;

  const int tid  = threadIdx.x;
  const int lane = tid & 63;
  const int w    = tid >> 6;
  const int wr   = w >> 2, wc = w & 3;

  const int rA  = tid >> 3;
  const int cSw = (tid ^ (tid >> 3)) & 7;

  const int aRow = wr * 16384 + (lane & 15) * 128;
  const int bRow = 32768 + (wc >> 1) * 16384 + ((wc & 1) * 64 + (lane & 15)) * 128;
  const int kq = (lane >> 4) * 16, sw = (lane & 7) << 4;
  const int kx0 = kq ^ sw;
  const int kx1 = (64 + kq) ^ sw;

  const int NT = K >> 6;
  const int NIT = NT >> 1;

  f32x4 acc[8][4] = {};
  Frags fr;

  auto stageA = [&](int half, int kt, int region) {
    const unsigned short* g = Ablk + ((long)(half * 128) + rA) * lda + (long)kt * 64 + cSw * 8;
    gload16(g,            sm + region + tid * 16);
    gload16(g + 64 * lda, sm + region + 8192 + tid * 16);
  };
  auto stageB = [&](int half, int kt, int region) {
    const unsigned short* g = Bblk + ((long)(half * 128) + rA) * ldb + (long)kt * 64 + cSw * 8;
    gload16(g,            sm + region + tid * 16);
    gload16(g + 64 * ldb, sm + region + 8192 + tid * 16);
  };

  stageA(0, 0, 0);
  stageA(1, 0, 16384);
  stageB(0, 0, 32768);
  stageB(1, 0, 49152);
  stageB(0, 1, 65536 + 32768);
  stageB(1, 1, 65536 + 49152);
  VMC4();
  SBAR();

#pragma unroll 1
  for (int it = 0; it < NIT; ++it) {
    const int kt1 = 2 * it + 1;
    const int kt2a = 2 * it + 2, kt2 = kt2a < NT ? kt2a : NT - 1;
    const int kt3a = 2 * it + 3, kt3 = kt3a < NT ? kt3a : NT - 1;

    qreads<0>(sm, 0, aRow, bRow, kx0, kx1, fr);
    stageA(0, kt1, 65536);
    SBAR(); LGKM0(); qmfma<0>(acc, fr); SBAR();

    qreads<1>(sm, 0, aRow, bRow, kx0, kx1, fr);
    stageA(1, kt1, 65536 + 16384);
    SBAR(); LGKM0(); qmfma<1>(acc, fr); SBAR();

    qreads<2>(sm, 0, aRow, bRow, kx0, kx1, fr);
    stageB(0, kt2, 32768);
    SBAR(); LGKM0(); qmfma<2>(acc, fr); SBAR();

    stageB(1, kt2, 49152);
    SBAR(); LGKM0(); qmfma<3>(acc, fr);
    VMC4();
    SBAR();

    qreads<0>(sm, 65536, aRow, bRow, kx0, kx1, fr);
    stageA(0, kt2, 0);
    SBAR(); LGKM0(); qmfma<0>(acc, fr); SBAR();

    qreads<1>(sm, 65536, aRow, bRow, kx0, kx1, fr);
    stageA(1, kt2, 16384);
    SBAR(); LGKM0(); qmfma<1>(acc, fr); SBAR();

    qreads<2>(sm, 65536, aRow, bRow, kx0, kx1, fr);
    stageB(0, kt3, 65536 + 32768);
    SBAR(); LGKM0(); qmfma<2>(acc, fr); SBAR();

    stageB(1, kt3, 65536 + 49152);
    SBAR(); LGKM0(); qmfma<3>(acc, fr);
    VMC4();
    SBAR();
  }

  // epilogue: C/D layout col = lane&15, row = (lane>>4)*4 + j
  const long crow0 = (long)mt * 256 + wr * 128;
  const long ccol0 = (long)nt * 256 + wc * 64;
  const long cbase = h * offC_h + bz * offC_b;
  const float* bptr = bias ? (bias + h * offBias_h + bz * offBias_b) : nullptr;

#pragma unroll
  for (int m = 0; m < 8; ++m)
#pragma unroll
    for (int n = 0; n < 4; ++n) {
      const long col = ccol0 + n * 16 + (lane & 15);
      const float cb = (EPI == 1) ? bptr[col] : 0.0f;
#pragma unroll
      for (int j = 0; j < 4; ++j) {
        const long row = crow0 + m * 16 + (lane >> 4) * 4 + j;
        float v = acc[m][n][j] * alpha;
        if constexpr (EPI == 1) v += cb;
        if constexpr (EPI == 2) v += bptr[row];
        if constexpr (EPI == 3) v = __expf(v);
        if constexpr (EPI == 4) v *= bptr[row];
        const long idx = cbase + row * ldc + col;
        if constexpr (EPI == 0) ((float*)C)[idx] = v;
        else                    ((unsigned short*)C)[idx] = f2bf(v);
      }
    }
}

// ---- rowsum: rinv[r] = 1 / sum(E[r][0..1023]); one wave per row --------------
__global__ __launch_bounds__(256)
void rowsum_k(const unsigned short* __restrict__ E, float* __restrict__ rinv)
{
  const int w = threadIdx.x >> 6, lane = threadIdx.x & 63;
  const long rrow = (long)blockIdx.x * 4 + w;
  const unsigned short* e = E + (rrow << 10) + lane * 16;
  float s = 0.0f;
#pragma unroll
  for (int t = 0; t < 2; ++t) {
    const uint4 v = *(const uint4*)(e + t * 8);
    s += bf2f((unsigned short)(v.x & 0xffff)) + bf2f((unsigned short)(v.x >> 16));
    s += bf2f((unsigned short)(v.y & 0xffff)) + bf2f((unsigned short)(v.y >> 16));
    s += bf2f((unsigned short)(v.z & 0xffff)) + bf2f((unsigned short)(v.z >> 16));
    s += bf2f((unsigned short)(v.w & 0xffff)) + bf2f((unsigned short)(v.w >> 16));
  }
#pragma unroll
  for (int o = 32; o >= 1; o >>= 1) s += __shfl_xor(s, o);
  if (lane == 0) rinv[rrow] = 1.0f / s;
}

// ---------------- converters / epilogue add -----------------------------------
// x [s][b][d] fp32 -> Xr [b][s][d] bf16
__global__ __launch_bounds__(256)
void conv_x(const float* __restrict__ in, unsigned short* __restrict__ out)
{
  const long i = (long)blockIdx.x * 256 + threadIdx.x;   // 2M float4
  const long o = i << 2;
  const long b = o >> 20, rem = o & 1048575;
  const long s = rem >> 10, d = rem & 1023;
  const float4 v = *(const float4*)(in + s * 8192 + b * 1024 + d);
  ushort4 u; u.x = f2bf(v.x); u.y = f2bf(v.y); u.z = f2bf(v.z); u.w = f2bf(v.w);
  *(ushort4*)(out + o) = u;
}

__global__ __launch_bounds__(256)
void conv_bf16(const float* __restrict__ in, unsigned short* __restrict__ out, long n4)
{
  const long i = (long)blockIdx.x * 256 + threadIdx.x;
  if (i >= n4) return;
  const float4 v = ((const float4*)in)[i];
  ushort4 o; o.x = f2bf(v.x); o.y = f2bf(v.y); o.z = f2bf(v.z); o.w = f2bf(v.w);
  ((ushort4*)out)[i] = o;
}

// w_out [h][f][e] -> Wob[f][h*1024+e]
__global__ __launch_bounds__(256)
void conv_wout(const float* __restrict__ in, unsigned short* __restrict__ out)
{
  const long i = (long)blockIdx.x * 256 + threadIdx.x;   // 2M float4s
  const long o = i << 2;
  const long f = o >> 13, r = o & 8191;
  const long h = r >> 10, e = r & 1023;
  const float4 v = *(const float4*)(in + h * 1048576 + f * 1024 + e);
  ushort4 u; u.x = f2bf(v.x); u.y = f2bf(v.y); u.z = f2bf(v.z); u.w = f2bf(v.w);
  *(ushort4*)(out + o) = u;
}

__global__ __launch_bounds__(256)
void bias_sum_k(const float* __restrict__ b_out, float* __restrict__ bsum)
{
  const int f = blockIdx.x * 256 + threadIdx.x;
  if (f < 1024) {
    float s = 0.f;
#pragma unroll
    for (int h = 0; h < 8; ++h) s += b_out[h * 1024 + f];
    bsum[f] = s;
  }
}

// out = p[0] + p[1] + bsum   (2M float4)
__global__ __launch_bounds__(256)
void add_out_k(const float* __restrict__ p, float* __restrict__ out,
               const float* __restrict__ bsum)
{
  const long i = (long)blockIdx.x * 256 + threadIdx.x;
  const float4 a = ((const float4*)p)[i];
  const float4 b = ((const float4*)(p + 8388608))[i];
  const float4 s = ((const float4*)bsum)[i & 255];
  float4 o;
  o.x = a.x + b.x + s.x; o.y = a.y + b.y + s.y;
  o.z = a.z + b.z + s.z; o.w = a.w + b.w + s.w;
  ((float4*)out)[i] = o;
}

// ---------------- launch ------------------------------------------------------
extern "C" void kernel_launch(void* const* d_in, const int* in_sizes, int n_in,
                              void* d_out, int out_size, void* d_ws, size_t ws_size,
                              hipStream_t stream)
{
  const float* x     = (const float*)d_in[0];
  const float* w_in  = (const float*)d_in[1];
  const float* b_in  = (const float*)d_in[2];
  const float* w_out = (const float*)d_in[3];
  const float* b_out = (const float*)d_in[4];
  float* out = (float*)d_out;

  char* ws = (char*)d_ws;
  const long MB = 1ll << 20;
  unsigned short* Xr    = (unsigned short*)(ws);              // 16 MiB [b][s][d]
  unsigned short* Wob   = (unsigned short*)(ws + 16 * MB);    // 16 MiB
  float*          bsum  = (float*)         (ws + 32 * MB);    // 4 KiB
  unsigned short* WbAll = (unsigned short*)(ws + 33 * MB);    // 48 MiB
  unsigned short* Ocat  = (unsigned short*)(ws + 81 * MB);    // 128 MiB
  unsigned short* QKg   = (unsigned short*)(ws + 209 * MB);   // 64 MiB [b*1024+s][hh*2048+u]
  unsigned short* E     = (unsigned short*)(ws + 273 * MB);   // 32 MiB [z][s][t]
  unsigned short* VT    = (unsigned short*)(ws + 305 * MB);   // 32 MiB [z][e][t]
  float*          rinv  = (float*)         (ws + 337 * MB);   // 64 KiB
  float*          Opart = (float*)QKg;                        // 64 MiB alias (QKg dead)

  dim3 blk(256), blk512(512);

  conv_x    <<<8192,  blk, 0, stream>>>(x, Xr);
  conv_bf16 <<<24576, blk, 0, stream>>>(w_in, WbAll, 6291456);
  conv_wout <<<8192,  blk, 0, stream>>>(w_out, Wob);
  bias_sum_k<<<4,     blk, 0, stream>>>(b_out, bsum);

  for (int g = 0; g < 4; ++g) {
    const long gW = (long)g * 6291456;     // 2 heads x 3072 x 1024
    const long gB = (long)g * 6144;

    // QK: z=hh: QKg[b*1024+s][hh*2048 + u] = Xr @ Wqk_hh^T + b_in, u<2048 (q,k)
    gemm256_nt<1,0><<<512, blk512, 0, stream>>>(
        Xr, WbAll + gW, QKg, b_in + gB, 1.0f, 1024,
        1024, 1024, 4096,  0, 0,  3145728, 0,  2048, 0,  3072, 0,  32, 8, 1);

    // VT: z=hh*8+b: VT[z][e][t] = Wv_hh @ Xr_b^T + bv[e] (row bias)
    gemm256_nt<2,0><<<256, blk512, 0, stream>>>(
        WbAll + gW + 2097152, Xr, VT, b_in + gB + 2048, 1.0f, 1024,
        1024, 1024, 1024,  3145728, 0,  0, 1048576,  8388608, 1048576,  3072, 0,  4, 4, 8);

    // scores: z=hh*8+b: E[z][s][t] = exp((Q K^T)/32)  bf16, unnormalized
    gemm256_nt<3,0><<<256, blk512, 0, stream>>>(
        QKg, QKg + 1024, E, nullptr, 0.03125f, 1024,
        4096, 4096, 1024,  2048, 4194304,  2048, 4194304,  8388608, 1048576,  0, 0,  4, 4, 8);

    // rinv[z][s] = 1/rowsum(E)
    rowsum_k<<<4096, blk, 0, stream>>>(E, rinv);

    // PV: Ocat[(s*8+b)*8192 + (2g+hh)*1024 + e] = rinv * sum_t E[z][s][t] VT[z][e][t]
    gemm256_nt<4,0><<<256, blk512, 0, stream>>>(
        E, VT, Ocat + (long)g * 2048, rinv, 1.0f, 1024,
        1024, 1024, 65536,  8388608, 1048576,  8388608, 1048576,  1024, 8192,  8192, 1024,  4, 4, 8);
  }

  // outproj K-split: Opart[z] = Ocat[:, z*4096:(z+1)*4096] @ Wob[:, same]^T
  gemm256_nt<0,1><<<256, blk512, 0, stream>>>(
      Ocat, Wob, Opart, nullptr, 1.0f, 4096,
      8192, 8192, 1024,  0, 4096,  0, 4096,  0, 8388608,  0, 0,  32, 4, 2);

  add_out_k<<<8192, blk, 0, stream>>>(Opart, out, bsum);
}